// Round 4
// baseline (219.787 us; speedup 1.0000x reference)
//
#include <hip/hip_runtime.h>
#include <stdint.h>

#define M_DIM 512
#define K_DIM 8192
#define N_DIM 14336
#define NGRP  64      // K / 128 groups
#define BN    64      // N columns per workgroup
#define NTILE (N_DIM / BN)   // 224

typedef int   i32x4  __attribute__((ext_vector_type(4)));
typedef int   i32x16 __attribute__((ext_vector_type(16)));
typedef float f32x4  __attribute__((ext_vector_type(4)));

// ---------------- Kernel 1: per-row dynamic int8 quantization ----------------
// Writes qA in MFMA-fragment-native layout:
//   qA[((g*16 + tile)*4 + ks)*1024 + l31*32 + lhi*16 + b]
// where row = tile*32 + l31, k = g*128 + ks*32 + lhi*16 + b.
__global__ __launch_bounds__(256) void quant_rows(const float* __restrict__ A,
                                                  uint8_t* __restrict__ qA,
                                                  float* __restrict__ s1)
{
    const int row  = blockIdx.x;
    const int tid  = threadIdx.x;
    const int tile = row >> 5;
    const int l31  = row & 31;
    const f32x4* src = (const f32x4*)(A + (size_t)row * K_DIM) + tid;

    f32x4 v[8];
#pragma unroll
    for (int i = 0; i < 8; ++i) v[i] = src[i * 256];

    float m = 0.0f;
#pragma unroll
    for (int i = 0; i < 8; ++i)
        m = fmaxf(m, fmaxf(fmaxf(fabsf(v[i].x), fabsf(v[i].y)),
                           fmaxf(fabsf(v[i].z), fabsf(v[i].w))));
#pragma unroll
    for (int off = 32; off > 0; off >>= 1)
        m = fmaxf(m, __shfl_xor(m, off));

    __shared__ float wmax[4];
    if ((tid & 63) == 0) wmax[tid >> 6] = m;
    __syncthreads();
    const float gm = fmaxf(fmaxf(wmax[0], wmax[1]), fmaxf(wmax[2], wmax[3]));
    const float s = gm / 127.0f;   // exact fp32 division, matches reference
    if (tid == 0) s1[row] = s;

#pragma unroll
    for (int i = 0; i < 8; ++i) {
        const int k0  = 4 * (tid + 256 * i);
        const int g   = k0 >> 7;
        const int ks  = (k0 >> 5) & 3;
        const int lhi = (k0 >> 4) & 1;
        const int b   = k0 & 15;
        uint32_t p = 0;
#pragma unroll
        for (int j = 0; j < 4; ++j) {
            float q = rintf(v[i][j] / s);             // round-half-even = np.round
            q = fminf(fmaxf(q, -128.0f), 127.0f);
            p |= ((uint32_t)(uint8_t)(int8_t)(int)q) << (8 * j);
        }
        *(uint32_t*)(qA + (size_t)(g * 16 + tile) * 4096 + ks * 1024
                        + l31 * 32 + lhi * 16 + b) = p;
    }
}

// ---------------- Kernel 2: w4 int32 -> int8 GEMM-native repack ----------------
// Output w8: per (ntile, g) an 8 KB tile that is the exact LDS image the GEMM
// DMAs: byte(col, k) = col*128 + (k ^ ((col & 7) << 4)),  col in [0,64), k in
// [0,128), value = w4[g*128+k][ntile*64+col] - 8 as int8. Pure streaming:
// coalesced 16B reads along n, 8B packed writes (L2 merges; tile fully written).
__global__ __launch_bounds__(256) void repack_w4(const int* __restrict__ w4,
                                                 uint8_t* __restrict__ w8)
{
    const int bx    = blockIdx.x;        // bx = ntile*64 + g
    const int ntile = bx >> 6;
    const int g     = bx & 63;
    const int t     = threadIdx.x;
    const int c4    = t & 15;            // column quad (cols c4*4 .. c4*4+3)
    const int kr    = t >> 4;            // 8-row chunk, 0..15 (k = kr*8 .. +7)

    const int* src = w4 + (size_t)(g * 128 + kr * 8) * N_DIM + ntile * 64 + c4 * 4;
    i32x4 r[8];
#pragma unroll
    for (int j = 0; j < 8; ++j)
        r[j] = *(const i32x4*)(src + (size_t)j * N_DIM);

    uint8_t* dst = w8 + (size_t)bx * 8192;
#pragma unroll
    for (int c = 0; c < 4; ++c) {
        const int col = c4 * 4 + c;
        uint32_t lo = ((uint32_t)(r[0][c] - 8) & 0xFFu)
                    | (((uint32_t)(r[1][c] - 8) & 0xFFu) << 8)
                    | (((uint32_t)(r[2][c] - 8) & 0xFFu) << 16)
                    | (((uint32_t)(r[3][c] - 8) & 0xFFu) << 24);
        uint32_t hi = ((uint32_t)(r[4][c] - 8) & 0xFFu)
                    | (((uint32_t)(r[5][c] - 8) & 0xFFu) << 8)
                    | (((uint32_t)(r[6][c] - 8) & 0xFFu) << 16)
                    | (((uint32_t)(r[7][c] - 8) & 0xFFu) << 24);
        // (kr*8) ^ swz stays 8-aligned (swz has only bits 4..6)
        uint2 v = make_uint2(lo, hi);
        *(uint2*)&dst[col * 128 + ((kr * 8) ^ ((col & 7) << 4))] = v;
    }
}

// ---------------- Kernel 3: lean W8A8 GEMM ----------------
// BM=256 (4 waves), BN=64, grid (224, 2) -> ~2 WGs/CU. B staged by verbatim
// 8 KB DMA of the pre-swizzled w8 tile into a 4-deep LDS ring (depth-3
// prefetch); qA fragments prefetched 1 group ahead into registers; s_group
// staged in LDS once. ONE barrier per group; counted vmcnt(12) drains only
// DMA(G+1), keeping DMA(G+2..3) + qA(G+1) in flight across the barrier.

#define DMA_PK(BUF, G) do {                                                    \
    const uint8_t* s0_ = w8 + ((size_t)ntile * 64 + (G)) * 8192               \
                         + wv * 1024 + lane * 16;                              \
    __builtin_amdgcn_global_load_lds(                                          \
        (const __attribute__((address_space(1))) void*)s0_,                    \
        (__attribute__((address_space(3))) void*)&pk[BUF][wv * 1024], 16, 0, 0);\
    __builtin_amdgcn_global_load_lds(                                          \
        (const __attribute__((address_space(1))) void*)(s0_ + 4096),           \
        (__attribute__((address_space(3))) void*)&pk[BUF][wv * 1024 + 4096],   \
        16, 0, 0);                                                             \
} while (0)

#define BODY(G, ACUR, ANXT) do {                                               \
    /* 1: prefetch A fragments for G+1 */                                      \
    { const int gn_ = ((G) + 1 < NGRP) ? (G) + 1 : NGRP - 1;                   \
      _Pragma("unroll")                                                        \
      for (int ms = 0; ms < 2; ++ms)                                           \
      _Pragma("unroll")                                                        \
      for (int ks = 0; ks < 4; ++ks)                                           \
          ANXT[ms][ks] = *(const i32x4*)(abase                                 \
              + (size_t)((gn_ * 16 + tile0 + ms) * 4 + ks) * 1024); }          \
    /* 2: issue DMA for G+3 */                                                 \
    { const int gd_ = ((G) + 3 < NGRP) ? (G) + 3 : NGRP - 1;                   \
      DMA_PK(((G) + 3) & 3, gd_); }                                            \
    /* 3: B fragments from pk[G&3] + group scales from LDS */                  \
    i32x4 bf_[2][4];                                                           \
    _Pragma("unroll")                                                          \
    for (int nt = 0; nt < 2; ++nt)                                             \
    _Pragma("unroll")                                                          \
    for (int ks = 0; ks < 4; ++ks)                                             \
        bf_[nt][ks] = *(const i32x4*)&pk[(G) & 3][(nt * 32 + l31) * 128        \
                        + ((ks * 32 + lhi * 16) ^ ((l31 & 7) << 4))];          \
    const float sg0_ = sgl[(G) * 64 + l31];                                    \
    const float sg1_ = sgl[(G) * 64 + 32 + l31];                               \
    /* 4: MFMA + per-group fp32 fold */                                        \
    _Pragma("unroll")                                                          \
    for (int nt = 0; nt < 2; ++nt) {                                           \
        const float sgv_ = nt ? sg1_ : sg0_;                                   \
        _Pragma("unroll")                                                      \
        for (int ms = 0; ms < 2; ++ms) {                                       \
            i32x16 ia = {0,0,0,0,0,0,0,0,0,0,0,0,0,0,0,0};                     \
            _Pragma("unroll")                                                  \
            for (int ks = 0; ks < 4; ++ks)                                     \
                ia = __builtin_amdgcn_mfma_i32_32x32x32_i8(ACUR[ms][ks],       \
                                                    bf_[nt][ks], ia, 0, 0, 0); \
            _Pragma("unroll")                                                  \
            for (int r = 0; r < 16; ++r)                                       \
                facc[ms][nt][r] += sgv_ * (float)ia[r];                        \
        }                                                                      \
    }                                                                          \
    /* 5: counted drain: only DMA(G+1) must be resident for next body */       \
    __builtin_amdgcn_sched_barrier(0);                                         \
    asm volatile("s_waitcnt vmcnt(12)" ::: "memory");                          \
    __builtin_amdgcn_sched_barrier(0);                                         \
    __builtin_amdgcn_s_barrier();                                              \
    __builtin_amdgcn_sched_barrier(0);                                         \
} while (0)

__global__ __launch_bounds__(256, 2) void w4a8_gemm(
    const uint8_t* __restrict__ qA, const float* __restrict__ s1,
    const uint8_t* __restrict__ w8, const float* __restrict__ sgrp,
    const float* __restrict__ schan, const float* __restrict__ bias,
    float* __restrict__ out)
{
    __shared__ uint8_t pk[4][8192];      // 32 KB: 4-deep B ring
    __shared__ float   sgl[NGRP * BN];   // 16 KB staged group scales

    const int tid   = threadIdx.x;
    const int lane  = tid & 63;
    const int wv    = tid >> 6;          // wave 0..3 -> rows [wv*64, wv*64+64)
    const int l31   = lane & 31;
    const int lhi   = lane >> 5;
    const int ntile = blockIdx.x;
    const int n0    = ntile * BN;
    const int mh    = blockIdx.y;        // m-half 0/1
    const int tile0 = mh * 8 + 2 * wv;   // first 32-row qA tile of this wave

    const uint8_t* abase = qA + l31 * 32 + lhi * 16;

    float facc[2][2][16];
#pragma unroll
    for (int a = 0; a < 2; ++a)
#pragma unroll
    for (int b = 0; b < 2; ++b)
#pragma unroll
    for (int r = 0; r < 16; ++r) facc[a][b][r] = 0.0f;

    // ---- prologue ----
#pragma unroll
    for (int j = 0; j < 16; ++j) {       // stage s_group for our 64 columns
        const int idx = tid + j * 256;   // idx = g*64 + c
        sgl[idx] = sgrp[(size_t)(idx >> 6) * N_DIM + n0 + (idx & 63)];
    }

    i32x4 aA[2][4], aB[2][4];
#pragma unroll
    for (int ms = 0; ms < 2; ++ms)
#pragma unroll
    for (int ks = 0; ks < 4; ++ks)
        aA[ms][ks] = *(const i32x4*)(abase
            + (size_t)((tile0 + ms) * 4 + ks) * 1024);

    __builtin_amdgcn_sched_barrier(0);
    DMA_PK(0, 0);
    DMA_PK(1, 1);
    DMA_PK(2, 2);
    __builtin_amdgcn_sched_barrier(0);
    asm volatile("s_waitcnt vmcnt(4)" ::: "memory");   // DMA(0) resident
    __builtin_amdgcn_sched_barrier(0);
    asm volatile("s_waitcnt lgkmcnt(0)" ::: "memory"); // sgl writes done
    __builtin_amdgcn_s_barrier();
    __builtin_amdgcn_sched_barrier(0);

    // ---- main loop: ping-pong A-fragment registers ----
#pragma unroll 1
    for (int g = 0; g < NGRP; g += 2) {
        BODY(g,     aA, aB);
        BODY(g + 1, aB, aA);
    }

    // ---- epilogue: D = facc * s1[m] * s_channel[n] + bias[n] ----
#pragma unroll
    for (int nt = 0; nt < 2; ++nt) {
        const int col = n0 + nt * 32 + l31;
        const float sch = schan[col];
        const float bv  = bias[col];
#pragma unroll
        for (int ms = 0; ms < 2; ++ms) {
            const int rbase = mh * 256 + wv * 64 + ms * 32 + 4 * lhi;
#pragma unroll
            for (int r = 0; r < 16; ++r) {
                const int row = rbase + (r & 3) + 8 * (r >> 2);
                out[(size_t)row * N_DIM + col] = facc[ms][nt][r] * s1[row] * sch + bv;
            }
        }
    }
}

extern "C" void kernel_launch(void* const* d_in, const int* in_sizes, int n_in,
                              void* d_out, int out_size, void* d_ws, size_t ws_size,
                              hipStream_t stream)
{
    const float* A     = (const float*)d_in[0];
    const int*   w4    = (const int*)  d_in[1];
    const float* sgrp  = (const float*)d_in[2];
    const float* schan = (const float*)d_in[3];
    const float* bias  = (const float*)d_in[4];
    float* out = (float*)d_out;

    // workspace: s1[512] @0, qA (4 MB, fragment-native) @4096,
    //            w8 (112 MB, GEMM-native tiles) @4096+4MB
    float*   s1 = (float*)d_ws;
    uint8_t* qA = (uint8_t*)d_ws + 4096;
    uint8_t* w8 = (uint8_t*)d_ws + 4096 + (size_t)M_DIM * K_DIM;

    quant_rows<<<dim3(M_DIM), dim3(256), 0, stream>>>(A, qA, s1);
    repack_w4<<<dim3(NTILE * NGRP), dim3(256), 0, stream>>>(w4, w8);
    w4a8_gemm<<<dim3(NTILE, 2), dim3(256), 0, stream>>>(qA, s1, w8, sgrp, schan, bias, out);
}